// Round 1
// baseline (79.925 us; speedup 1.0000x reference)
//
#include <hip/hip_runtime.h>
#include <math.h>

#define KK 8

// ---------------------------------------------------------------------------
// Kernel 1: one block per mixture row m (512 threads = 8 waves).
//  - threads 0..7 precompute per-component params into LDS
//  - every thread processes 8 of the B=4096 X rows (2 chunks of 4)
//  - block-reduces responsibilities, writes z[m, 0:80] fully
// z layout per row (80): [mu(32) | logL(32) | pi(8) | resp(8)]
// ---------------------------------------------------------------------------
__global__ __launch_bounds__(512) void gmm_main(const float* __restrict__ phi,
                                                const float* __restrict__ X,
                                                float* __restrict__ zbuf,
                                                int B) {
    __shared__ float4 sp[KK][4];   // per-k params, broadcast reads
    __shared__ float swr[8][KK];   // per-wave resp partials

    const int m = blockIdx.x;
    const int t = threadIdx.x;
    const float* row = phi + m * 120;

    if (t < KK) {
        // softmax over pi_tilde (redundant per thread, 8 threads, cheap)
        float mx = row[0];
        #pragma unroll
        for (int j = 1; j < KK; ++j) mx = fmaxf(mx, row[j]);
        float s = 0.f;
        #pragma unroll
        for (int j = 0; j < KK; ++j) s += expf(row[j] - mx);
        float pik = expf(row[t] - mx) / s;

        const float* muk = row + 8 + t * 4;
        const float* Lv  = row + 40 + t * 10;
        // tril order for D=4: (0,0)(1,0)(1,1)(2,0)(2,1)(2,2)(3,0)(3,1)(3,2)(3,3)
        float l00 = Lv[0], l10 = Lv[1], l11 = Lv[2], l20 = Lv[3], l21 = Lv[4],
              l22 = Lv[5], l30 = Lv[6], l31 = Lv[7], l32 = Lv[8], l33 = Lv[9];
        float i0 = 1.f / l00, i1 = 1.f / l11, i2 = 1.f / l22, i3 = 1.f / l33;
        float logdet = 2.f * (logf(fmaxf(fabsf(l00), 1e-8f)) +
                              logf(fmaxf(fabsf(l11), 1e-8f)) +
                              logf(fmaxf(fabsf(l22), 1e-8f)) +
                              logf(fmaxf(fabsf(l33), 1e-8f)));
        // c = log(clip(pi)) - 0.5*(D*log(2pi) + logdet)
        float c = logf(fmaxf(pik, 1e-8f)) -
                  0.5f * (4.f * 1.8378770664093453f + logdet);
        sp[t][0] = make_float4(muk[0], muk[1], muk[2], muk[3]);
        sp[t][1] = make_float4(l10, l20, l21, l30);
        sp[t][2] = make_float4(l31, l32, i1, i2);
        sp[t][3] = make_float4(i3, c, i0, 0.f);
    }

    // z prefix: mu_flat, log_L_flat (clip 1e-6), pi
    if (t < 32) {
        zbuf[m * 80 + t] = row[8 + t];
    } else if (t < 64) {
        int j = t - 32, k = j >> 2, d = j & 3;
        int didx = (d == 0) ? 0 : (d == 1) ? 2 : (d == 2) ? 5 : 9;
        zbuf[m * 80 + t] = logf(fmaxf(fabsf(row[40 + k * 10 + didx]), 1e-6f));
    } else if (t < 72) {
        int k = t - 64;
        float mx = row[0];
        #pragma unroll
        for (int j = 1; j < KK; ++j) mx = fmaxf(mx, row[j]);
        float s = 0.f;
        #pragma unroll
        for (int j = 0; j < KK; ++j) s += expf(row[j] - mx);
        zbuf[m * 80 + t] = expf(row[k] - mx) / s;
    }
    __syncthreads();

    float acc[KK];
    #pragma unroll
    for (int k = 0; k < KK; ++k) acc[k] = 0.f;

    const float4* X4 = reinterpret_cast<const float4*>(X);
    for (int base = 0; base < B; base += 2048) {
        float4 xv[4];
        #pragma unroll
        for (int i = 0; i < 4; ++i) xv[i] = X4[base + i * 512 + t];

        float lj[4][KK];
        #pragma unroll
        for (int k = 0; k < KK; ++k) {
            float4 p0 = sp[k][0], p1 = sp[k][1], p2 = sp[k][2], p3 = sp[k][3];
            // mu=p0; l10,l20,l21,l30=p1; l31,l32,i1,i2=p2; i3,c,i0=p3
            #pragma unroll
            for (int i = 0; i < 4; ++i) {
                float d0 = xv[i].x - p0.x;
                float d1 = xv[i].y - p0.y;
                float d2 = xv[i].z - p0.z;
                float d3 = xv[i].w - p0.w;
                float a0 = d0 * p3.z;
                float a1 = (d1 - p1.x * a0) * p2.z;
                float a2 = (d2 - p1.y * a0 - p1.z * a1) * p2.w;
                float a3 = (d3 - p1.w * a0 - p2.x * a1 - p2.y * a2) * p3.x;
                float maha = a0 * a0 + a1 * a1 + a2 * a2 + a3 * a3;
                lj[i][k] = p3.y - 0.5f * maha;
            }
        }
        #pragma unroll
        for (int i = 0; i < 4; ++i) {
            float mx = lj[i][0];
            #pragma unroll
            for (int k = 1; k < KK; ++k) mx = fmaxf(mx, lj[i][k]);
            float e[KK], s = 0.f;
            #pragma unroll
            for (int k = 0; k < KK; ++k) { e[k] = __expf(lj[i][k] - mx); s += e[k]; }
            float inv = 1.f / s;  // s >= 1 (max term contributes 1)
            #pragma unroll
            for (int k = 0; k < KK; ++k) acc[k] += e[k] * inv;
        }
    }

    // block reduction of resp accumulators
    #pragma unroll
    for (int k = 0; k < KK; ++k) {
        float v = acc[k];
        #pragma unroll
        for (int off = 32; off; off >>= 1) v += __shfl_xor(v, off, 64);
        acc[k] = v;
    }
    if ((t & 63) == 0) {
        int wid = t >> 6;
        #pragma unroll
        for (int k = 0; k < KK; ++k) swr[wid][k] = acc[k];
    }
    __syncthreads();
    if (t < KK) {
        float s = 0.f;
        #pragma unroll
        for (int w = 0; w < 8; ++w) s += swr[w][t];
        zbuf[m * 80 + 72 + t] = s / (float)B;
    }
}

// ---------------------------------------------------------------------------
// Kernel 2: column-wise normalization of z (M rows x 80 cols), ddof=1.
// One block per column, 512 threads (one row each for M=512).
// ---------------------------------------------------------------------------
__global__ __launch_bounds__(512) void gmm_norm(const float* __restrict__ zbuf,
                                                float* __restrict__ out, int M) {
    __shared__ float sw[8];
    const int col = blockIdx.x;
    const int t = threadIdx.x;

    float s = 0.f;
    for (int r = t; r < M; r += 512) s += zbuf[r * 80 + col];
    float v = s;
    #pragma unroll
    for (int off = 32; off; off >>= 1) v += __shfl_xor(v, off, 64);
    if ((t & 63) == 0) sw[t >> 6] = v;
    __syncthreads();
    float tot = 0.f;
    #pragma unroll
    for (int w = 0; w < 8; ++w) tot += sw[w];
    float mean = tot / (float)M;
    __syncthreads();

    float s2 = 0.f;
    for (int r = t; r < M; r += 512) {
        float d = zbuf[r * 80 + col] - mean;
        s2 += d * d;
    }
    v = s2;
    #pragma unroll
    for (int off = 32; off; off >>= 1) v += __shfl_xor(v, off, 64);
    if ((t & 63) == 0) sw[t >> 6] = v;
    __syncthreads();
    float tot2 = 0.f;
    #pragma unroll
    for (int w = 0; w < 8; ++w) tot2 += sw[w];
    float stdv = fmaxf(sqrtf(tot2 / (float)(M - 1)), 1e-6f);
    float invstd = 1.f / stdv;

    for (int r = t; r < M; r += 512)
        out[r * 80 + col] = (zbuf[r * 80 + col] - mean) * invstd;
}

extern "C" void kernel_launch(void* const* d_in, const int* in_sizes, int n_in,
                              void* d_out, int out_size, void* d_ws, size_t ws_size,
                              hipStream_t stream) {
    const float* phi = (const float*)d_in[0];
    const float* X   = (const float*)d_in[1];
    const int M = in_sizes[0] / 120;  // 512
    const int B = in_sizes[1] / 4;    // 4096
    float* zbuf = (float*)d_ws;       // M*80 floats

    gmm_main<<<M, 512, 0, stream>>>(phi, X, zbuf, B);
    gmm_norm<<<80, 512, 0, stream>>>(zbuf, (float*)d_out, M);
}

// Round 2
// 77.655 us; speedup vs baseline: 1.0292x; 1.0292x over previous
//
#include <hip/hip_runtime.h>
#include <math.h>

#define KK 8
#define LOG2E  1.4426950408889634f
#define HL2E   0.7213475204444817f   // 0.5 * log2(e)
#define LOG2PI 1.8378770664093453f

// ---------------------------------------------------------------------------
// Kernel 1: one block per mixture row m (512 threads = 8 waves).
// Writes all 80 z-columns of row m directly into d_out:
//   [mu(32) | logL(32) | pi(8) | resp(8)]
// Log-densities kept in log2 domain so softmax uses bare v_exp_f32.
// ---------------------------------------------------------------------------
__global__ __launch_bounds__(512) void gmm_main(const float* __restrict__ phi,
                                                const float* __restrict__ X,
                                                float* __restrict__ z,
                                                int B) {
    __shared__ float4 sp[KK][4];   // per-component params (broadcast reads)
    __shared__ float swr[8][KK];   // per-wave resp partials

    const int m = blockIdx.x;
    const int t = threadIdx.x;
    const float* row = phi + m * 120;

    if (t < KK) {
        // softmax over pi_tilde (redundant across 8 threads, cheap)
        float mx = row[0];
        #pragma unroll
        for (int j = 1; j < KK; ++j) mx = fmaxf(mx, row[j]);
        float s = 0.f;
        #pragma unroll
        for (int j = 0; j < KK; ++j) s += __expf(row[j] - mx);
        float pik = __expf(row[t] - mx) / s;
        z[m * 80 + 64 + t] = pik;                       // pi columns

        const float* muk = row + 8 + t * 4;
        const float* Lv  = row + 40 + t * 10;
        // tril(D=4) order: l00,l10,l11,l20,l21,l22,l30,l31,l32,l33
        float l00 = Lv[0], l10 = Lv[1], l11 = Lv[2], l20 = Lv[3], l21 = Lv[4],
              l22 = Lv[5], l30 = Lv[6], l31 = Lv[7], l32 = Lv[8], l33 = Lv[9];
        float i0 = 1.f / l00, i1 = 1.f / l11, i2 = 1.f / l22, i3 = 1.f / l33;
        float logdet = 2.f * (__logf(fmaxf(fabsf(l00), 1e-8f)) +
                              __logf(fmaxf(fabsf(l11), 1e-8f)) +
                              __logf(fmaxf(fabsf(l22), 1e-8f)) +
                              __logf(fmaxf(fabsf(l33), 1e-8f)));
        // c2 = log2-domain constant: (log(pi) - 0.5*(D*log2pi + logdet)) * log2e
        float c2 = (__logf(fmaxf(pik, 1e-8f)) -
                    0.5f * (4.f * LOG2PI + logdet)) * LOG2E;
        sp[t][0] = make_float4(muk[0], muk[1], muk[2], muk[3]);
        sp[t][1] = make_float4(l10, l20, l21, l30);
        sp[t][2] = make_float4(l31, l32, i1, i2);
        sp[t][3] = make_float4(i3, c2, i0, 0.f);
    } else if (t >= 64 && t < 96) {                     // mu columns
        int j = t - 64;
        z[m * 80 + j] = row[8 + j];
    } else if (t >= 96 && t < 128) {                    // log|L_diag| columns
        int j = t - 96, k = j >> 2, d = j & 3;
        int didx = (d == 0) ? 0 : (d == 1) ? 2 : (d == 2) ? 5 : 9;
        z[m * 80 + 32 + j] = __logf(fmaxf(fabsf(row[40 + k * 10 + didx]), 1e-6f));
    }
    __syncthreads();

    float acc[KK];
    #pragma unroll
    for (int k = 0; k < KK; ++k) acc[k] = 0.f;

    const float4* X4 = reinterpret_cast<const float4*>(X);
    for (int base = 0; base < B; base += 2048) {
        float4 xv[4];
        #pragma unroll
        for (int i = 0; i < 4; ++i) xv[i] = X4[base + i * 512 + t];

        float lj[4][KK];
        #pragma unroll
        for (int k = 0; k < KK; ++k) {
            float4 p0 = sp[k][0], p1 = sp[k][1], p2 = sp[k][2], p3 = sp[k][3];
            // mu=p0; l10,l20,l21,l30=p1; l31,l32,i1,i2=p2; i3,c2,i0=p3
            #pragma unroll
            for (int i = 0; i < 4; ++i) {
                float d0 = xv[i].x - p0.x;
                float d1 = xv[i].y - p0.y;
                float d2 = xv[i].z - p0.z;
                float d3 = xv[i].w - p0.w;
                float a0 = d0 * p3.z;
                float a1 = (d1 - p1.x * a0) * p2.z;
                float a2 = (d2 - p1.y * a0 - p1.z * a1) * p2.w;
                float a3 = (d3 - p1.w * a0 - p2.x * a1 - p2.y * a2) * p3.x;
                float sq = fmaf(a0, a0, fmaf(a1, a1, fmaf(a2, a2, a3 * a3)));
                lj[i][k] = fmaf(-HL2E, sq, p3.y);        // log2-domain
            }
        }
        #pragma unroll
        for (int i = 0; i < 4; ++i) {
            float mx = lj[i][0];
            #pragma unroll
            for (int k = 1; k < KK; ++k) mx = fmaxf(mx, lj[i][k]);
            float e[KK], s = 0.f;
            #pragma unroll
            for (int k = 0; k < KK; ++k) { e[k] = exp2f(lj[i][k] - mx); s += e[k]; }
            float inv = __builtin_amdgcn_rcpf(s);        // s >= 1
            #pragma unroll
            for (int k = 0; k < KK; ++k) acc[k] = fmaf(e[k], inv, acc[k]);
        }
    }

    // block reduction of resp accumulators
    #pragma unroll
    for (int k = 0; k < KK; ++k) {
        float v = acc[k];
        #pragma unroll
        for (int off = 32; off; off >>= 1) v += __shfl_xor(v, off, 64);
        acc[k] = v;
    }
    if ((t & 63) == 0) {
        int wid = t >> 6;
        #pragma unroll
        for (int k = 0; k < KK; ++k) swr[wid][k] = acc[k];
    }
    __syncthreads();
    if (t < KK) {
        float s = 0.f;
        #pragma unroll
        for (int w = 0; w < 8; ++w) s += swr[w][t];
        z[m * 80 + 72 + t] = s / (float)B;               // resp columns
    }
}

// ---------------------------------------------------------------------------
// Kernel 2: in-place column normalization of z (M=512 rows x 80 cols), ddof=1.
// One block per column, one thread per row; element cached in a register.
// ---------------------------------------------------------------------------
__global__ __launch_bounds__(512) void gmm_norm(float* __restrict__ z, int M) {
    __shared__ float sw[8];
    const int col = blockIdx.x;
    const int t = threadIdx.x;

    float v = z[t * 80 + col];

    float r = v;
    #pragma unroll
    for (int off = 32; off; off >>= 1) r += __shfl_xor(r, off, 64);
    if ((t & 63) == 0) sw[t >> 6] = r;
    __syncthreads();
    float tot = 0.f;
    #pragma unroll
    for (int w = 0; w < 8; ++w) tot += sw[w];
    float mean = tot / (float)M;
    __syncthreads();

    float d = v - mean;
    r = d * d;
    #pragma unroll
    for (int off = 32; off; off >>= 1) r += __shfl_xor(r, off, 64);
    if ((t & 63) == 0) sw[t >> 6] = r;
    __syncthreads();
    float tot2 = 0.f;
    #pragma unroll
    for (int w = 0; w < 8; ++w) tot2 += sw[w];
    float stdv = fmaxf(sqrtf(tot2 / (float)(M - 1)), 1e-6f);

    z[t * 80 + col] = d / stdv;
}

extern "C" void kernel_launch(void* const* d_in, const int* in_sizes, int n_in,
                              void* d_out, int out_size, void* d_ws, size_t ws_size,
                              hipStream_t stream) {
    const float* phi = (const float*)d_in[0];
    const float* X   = (const float*)d_in[1];
    const int M = in_sizes[0] / 120;  // 512
    const int B = in_sizes[1] / 4;    // 4096
    float* z = (float*)d_out;         // z staged directly in d_out

    gmm_main<<<M, 512, 0, stream>>>(phi, X, z, B);
    gmm_norm<<<80, 512, 0, stream>>>(z, M);
}